// Round 13
// baseline (2292.811 us; speedup 1.0000x reference)
//
#include <hip/hip_runtime.h>
#include <math.h>

#define TT 1024
#define BB 64
#define II 128
#define HH 256
#define OO 128
#define GPB 16
#define ZSH 264          // h strip stride (floats)
#define XBS 132          // x strip stride (floats)
#define PART_BG_STRIDE 68
#define PART_RC_STRIDE 273

// ws layout: abort @int 0; tagged hbuf [2][64][256] u64 @byte 16384 (256KB)
#define WS_HBUF_B 16384
#define WS_CLEAR_B (WS_HBUF_B + 2 * BB * HH * 8)

typedef unsigned long long u64;
typedef unsigned int u32;

__device__ __forceinline__ float rcp(float v) { return __builtin_amdgcn_rcpf(v); }
__device__ __forceinline__ float sigm(float v) { return rcp(1.f + __expf(-v)); }
__device__ __forceinline__ float ftanh(float v) {
    return __builtin_fmaf(-2.f, rcp(__expf(2.f * v) + 1.f), 1.f);
}
#define HLOAD(p) __hip_atomic_load((p), __ATOMIC_RELAXED, __HIP_MEMORY_SCOPE_AGENT)

extern "C" __global__ void __launch_bounds__(256, 1) lstm_scan(
    const float* __restrict__ x, const float* __restrict__ W,
    const float* __restrict__ U, const float* __restrict__ bias,
    float* __restrict__ wsf)
{
    __shared__ float z[4 * ZSH];          // h_{t-1} strips, one per wave/batch
    __shared__ float xb[2][4 * XBS];      // double-buffered x_t strips
    __shared__ float part[16 * PART_RC_STRIDE];
    __shared__ int   misc[8];

    int* abortp = (int*)wsf;
    u64* hbuf   = (u64*)((char*)wsf + WS_HBUF_B);   // [2][64][256] tagged

    const int tid  = threadIdx.x;
    const int gid  = blockIdx.x & 15;     // group
    const int p    = blockIdx.x >> 4;     // member: owns h-indices [16p,16p+16)
    const int cg   = tid & 15;            // column group (4 logical cols)
    const int rc   = tid >> 4;            // row group
    const int lane = tid & 63;
    const int w    = tid >> 6;            // wave == batch slot in group
    const int myb  = 4 * gid + w;
    const int j    = lane & 15;
    const int b2   = tid >> 5;            // x-stage batch (tid<128)
    const int l2   = tid & 31;            // x-stage float4 index

    // weights in VGPRs/L2: wr[rr][i][c] = [W;U][rr*64+rc*4+i][cg*4+c-mapped]
    float wr[6][4][4];
    {
        const int c0 = cg * 4;
        const int gcol = (c0 >> 4) * HH + p * 16 + (c0 & 15);
#pragma unroll
        for (int rr = 0; rr < 6; ++rr)
#pragma unroll
            for (int i = 0; i < 4; ++i) {
                const int r = rr * 64 + rc * 4 + i;
                const float4 wv = (rr < 2)
                    ? *(const float4*)(W + (size_t)r * 1024 + gcol)
                    : *(const float4*)(U + (size_t)(r - II) * 1024 + gcol);
                wr[rr][i][0] = wv.x; wr[rr][i][1] = wv.y;
                wr[rr][i][2] = wv.z; wr[rr][i][3] = wv.w;
            }
    }
    const float bia_reg = bias[(lane >> 4) * HH + p * 16 + j];
    float creg = 0.f;                     // c-state: lanes 0..15 of each wave

    for (int idx = tid; idx < 4 * ZSH; idx += 256) z[idx] = 0.f;
    if (tid < 8) misc[tid] = 0;
    // stage x_1 into xb[1]
    if (tid < 128) {
        const float4 xv = *(const float4*)(
            x + ((size_t)(4 * gid + b2) * TT + 0) * II + 4 * l2);
        *(float4*)(&xb[1][b2 * XBS + 4 * l2]) = xv;
    }
    __syncthreads();

    for (int t = 1; t <= TT; ++t) {
        // ---- P0: issue x_{t+1} loads (latency hides under poll + h-matvec)
        float4 xnext;
        if (t < TT && tid < 128)
            xnext = *(const float4*)(
                x + ((size_t)(4 * gid + b2) * TT + t) * II + 4 * l2);

        // ---- x-dot from xb[t&1] (h-independent, before the wait)
        float acc[4][4];
#pragma unroll
        for (int a = 0; a < 4; ++a)
#pragma unroll
            for (int b = 0; b < 4; ++b) acc[a][b] = 0.f;
        {
            const float* xcur = xb[t & 1];
#pragma unroll
            for (int rr = 0; rr < 2; ++rr)
#pragma unroll
                for (int bg = 0; bg < 4; ++bg) {
                    const float4 zv = *(const float4*)(xcur + bg * XBS + rr * 64 + rc * 4);
#pragma unroll
                    for (int c = 0; c < 4; ++c)
                        acc[bg][c] += zv.x * wr[rr][0][c] + zv.y * wr[rr][1][c]
                                    + zv.z * wr[rr][2][c] + zv.w * wr[rr][3][c];
                }
        }

        // ---- staggered tagged poll: 2 load-sets in flight, detect == data
        if (t > 1) {
            const u32 want = (u32)(t - 1);
            const u64* hsrc = hbuf + ((size_t)((t - 1) & 1) * BB + myb) * HH;
            u64 n0, n1, n2, n3;
            u64 a0 = HLOAD(hsrc + lane),       a1 = HLOAD(hsrc + lane + 64),
                a2 = HLOAD(hsrc + lane + 128), a3 = HLOAD(hsrc + lane + 192);
            int it = 0, ab = 0;
            for (;;) {
                u64 c0 = HLOAD(hsrc + lane),       c1 = HLOAD(hsrc + lane + 64),
                    c2 = HLOAD(hsrc + lane + 128), c3 = HLOAD(hsrc + lane + 192);
                bool ok = ((u32)(a0 >> 32) == want) && ((u32)(a1 >> 32) == want)
                       && ((u32)(a2 >> 32) == want) && ((u32)(a3 >> 32) == want);
                if (__ballot(ok) == ~0ULL) { n0 = a0; n1 = a1; n2 = a2; n3 = a3; break; }
                a0 = HLOAD(hsrc + lane);       a1 = HLOAD(hsrc + lane + 64);
                a2 = HLOAD(hsrc + lane + 128); a3 = HLOAD(hsrc + lane + 192);
                ok = ((u32)(c0 >> 32) == want) && ((u32)(c1 >> 32) == want)
                  && ((u32)(c2 >> 32) == want) && ((u32)(c3 >> 32) == want);
                if (__ballot(ok) == ~0ULL) { n0 = c0; n1 = c1; n2 = c2; n3 = c3; break; }
                if ((++it & 63) == 0) {
                    int abv = HLOAD(abortp);
                    if (abv) { ab = 1; break; }
                    if (it > (1 << 19)) {
                        if (lane == 0)
                            __hip_atomic_store(abortp, 1, __ATOMIC_RELAXED,
                                               __HIP_MEMORY_SCOPE_AGENT);
                        ab = 1; break;
                    }
                }
            }
            if (ab) { if (lane == 0) misc[w] = 1; n0 = n1 = n2 = n3 = 0; }
            float* zdst = z + w * ZSH + lane;
            zdst[0]   = __uint_as_float((u32)n0);
            zdst[64]  = __uint_as_float((u32)n1);
            zdst[128] = __uint_as_float((u32)n2);
            zdst[192] = __uint_as_float((u32)n3);
        }
        __syncthreads();                         // B1: z strips ready
        if (misc[0] | misc[1] | misc[2] | misc[3]) break;

        // ---- P1: h-matvec (rows 128..383 -> wr[2..5], z strips)
#pragma unroll
        for (int rrh = 0; rrh < 4; ++rrh)
#pragma unroll
            for (int bg = 0; bg < 4; ++bg) {
                const float4 zv = *(const float4*)(z + bg * ZSH + rrh * 64 + rc * 4);
#pragma unroll
                for (int c = 0; c < 4; ++c)
                    acc[bg][c] += zv.x * wr[rrh + 2][0][c] + zv.y * wr[rrh + 2][1][c]
                                + zv.z * wr[rrh + 2][2][c] + zv.w * wr[rrh + 2][3][c];
            }

        // stage x_{t+1} into the other xb buffer (read next iter after B2)
        if (t < TT && tid < 128)
            *(float4*)(&xb[(t + 1) & 1][b2 * XBS + 4 * l2]) = xnext;

        // ---- partials to LDS
#pragma unroll
        for (int bg = 0; bg < 4; ++bg)
#pragma unroll
            for (int c = 0; c < 4; ++c)
                part[rc * PART_RC_STRIDE + bg * PART_BG_STRIDE + cg * 4 + c] = acc[bg][c];
        __syncthreads();                         // B2: partials + xb ready

        // ---- P2: per-wave reduce + shfl gates + tagged publish (no barrier)
        float s = bia_reg;
#pragma unroll
        for (int r2 = 0; r2 < 16; ++r2)
            s += part[r2 * PART_RC_STRIDE + w * PART_BG_STRIDE + lane];

        const float sf = __shfl(s, j + 16);
        const float sg = __shfl(s, j + 32);
        const float so = __shfl(s, j + 48);
        if (lane < 16) {
            const float iv = sigm(s);
            const float fv = sigm(sf);
            const float gv = ftanh(sg);
            const float ov = sigm(so);
            creg = fv * creg + iv * gv;
            const float hv = ov * ftanh(creg);
            const u64 pk = ((u64)(u32)t << 32) | (u64)__float_as_uint(hv);
            __hip_atomic_store(
                hbuf + ((size_t)(t & 1) * BB + myb) * HH + p * 16 + j,
                pk, __ATOMIC_RELAXED, __HIP_MEMORY_SCOPE_AGENT);
        }
    }
}

extern "C" __global__ void __launch_bounds__(256) lstm_out(
    const float* __restrict__ wsf, const float* __restrict__ dw,
    const float* __restrict__ db, float* __restrict__ out)
{
    __shared__ float hs[256];
    __shared__ float red[256];
    const int b = blockIdx.x;
    const int tid = threadIdx.x;
    const u64* h0 = (const u64*)((const char*)wsf + WS_HBUF_B);  // parity 0 = h_1024
    hs[tid] = __uint_as_float((u32)h0[(size_t)b * HH + tid]);
    __syncthreads();
    const int o = tid & 127, half = tid >> 7;
    const float* wrow = dw + o * HH + half * 128;
    const float* hrow = hs + half * 128;
    float s = 0.f;
#pragma unroll
    for (int k = 0; k < 128; k += 4) {
        const float4 wv = *(const float4*)(wrow + k);
        s += hrow[k] * wv.x + hrow[k + 1] * wv.y + hrow[k + 2] * wv.z + hrow[k + 3] * wv.w;
    }
    red[tid] = s;
    __syncthreads();
    if (tid < 128)
        out[(size_t)b * OO + tid] = red[tid] + red[128 + tid] + db[tid];
}

extern "C" void kernel_launch(void* const* d_in, const int* in_sizes, int n_in,
                              void* d_out, int out_size, void* d_ws, size_t ws_size,
                              hipStream_t stream)
{
    const float* x    = (const float*)d_in[0];
    const float* W    = (const float*)d_in[1];
    const float* U    = (const float*)d_in[2];
    const float* bias = (const float*)d_in[3];
    const float* dw   = (const float*)d_in[4];
    const float* db   = (const float*)d_in[5];
    float* out = (float*)d_out;
    float* ws  = (float*)d_ws;

    // zero abort + tagged hbuf each call (tag=0 never matches t>=1)
    hipMemsetAsync(d_ws, 0, WS_CLEAR_B, stream);
    hipLaunchKernelGGL(lstm_scan, dim3(256), dim3(256), 0, stream,
                       x, W, U, bias, ws);
    hipLaunchKernelGGL(lstm_out, dim3(64), dim3(256), 0, stream, ws, dw, db, out);
}

// Round 14
// 2207.830 us; speedup vs baseline: 1.0385x; 1.0385x over previous
//
#include <hip/hip_runtime.h>
#include <math.h>

#define TT 1024
#define BB 64
#define II 128
#define HH 256
#define OO 128
#define Z_STRIDE 392     // per-batch strip: x(128) + pad + h(256)
#define PART_BG_STRIDE 68
#define PART_RC_STRIDE 137   // 2 batches * 68 + 1 (odd -> bank-spread)

// ws layout: abort @int 0; tagged hbuf [2][64][256] u64 @byte 16384 (256KB)
#define WS_HBUF_B 16384
#define WS_CLEAR_B (WS_HBUF_B + 2 * BB * HH * 8)

typedef unsigned long long u64;
typedef unsigned int u32;

__device__ __forceinline__ float rcp(float v) { return __builtin_amdgcn_rcpf(v); }
__device__ __forceinline__ float sigm(float v) { return rcp(1.f + __expf(-v)); }
__device__ __forceinline__ float ftanh(float v) {
    return __builtin_fmaf(-2.f, rcp(__expf(2.f * v) + 1.f), 1.f);
}
#define HLOAD(p) __hip_atomic_load((p), __ATOMIC_RELAXED, __HIP_MEMORY_SCOPE_AGENT)

// 512 blocks = 32 groups x 16 members; group g handles batches {2g, 2g+1};
// member p owns h-dims [16p, 16p+16). blockIdx = p*32 + g -> all members of a
// group land on one XCD (blockIdx%8 == g%8 under round-robin dispatch; perf-only).
// 2 blocks/CU: the CU overlaps one block's poll wait with the other's compute.
extern "C" __global__ void __launch_bounds__(256, 2) lstm_scan(
    const float* __restrict__ x, const float* __restrict__ W,
    const float* __restrict__ U, const float* __restrict__ bias,
    float* __restrict__ wsf)
{
    __shared__ float z[2 * Z_STRIDE];
    __shared__ float part[16 * PART_RC_STRIDE];
    __shared__ int   misc[8];

    int* abortp = (int*)wsf;
    u64* hbuf   = (u64*)((char*)wsf + WS_HBUF_B);   // [2][64][256] tagged

    const int tid  = threadIdx.x;
    const int g    = blockIdx.x & 31;     // group
    const int p    = blockIdx.x >> 5;     // member: owns h-dims [16p,16p+16)
    const int cg   = tid & 15;            // column group (4 logical cols)
    const int rc   = tid >> 4;            // row group
    const int lane = tid & 63;
    const int w    = tid >> 6;            // wave; w<2 => batch slot w
    const int myb  = 2 * g + (w & 1);     // this wave's batch (valid for w<2)
    const int j    = lane & 15;

    // weights in VGPRs: wr[rr][i][c] = [W;U][rr*64+rc*4+i][col(cg*4+c)]
    float wr[6][4][4];
    {
        const int c0 = cg * 4;
        const int gcol = (c0 >> 4) * HH + p * 16 + (c0 & 15);
#pragma unroll
        for (int rr = 0; rr < 6; ++rr)
#pragma unroll
            for (int i = 0; i < 4; ++i) {
                const int r = rr * 64 + rc * 4 + i;
                const float4 wv = (rr < 2)
                    ? *(const float4*)(W + (size_t)r * 1024 + gcol)
                    : *(const float4*)(U + (size_t)(r - II) * 1024 + gcol);
                wr[rr][i][0] = wv.x; wr[rr][i][1] = wv.y;
                wr[rr][i][2] = wv.z; wr[rr][i][3] = wv.w;
            }
    }
    const float bia_reg = bias[(lane >> 4) * HH + p * 16 + j];
    float creg = 0.f;                     // c-state: lanes 0..15 of waves 0,1

    for (int idx = tid; idx < 2 * Z_STRIDE; idx += 256) z[idx] = 0.f;
    if (tid < 8) misc[tid] = 0;
    // stage x_1 for both batches (threads 0..63)
    if (tid < 64) {
        const int b2 = tid >> 5, l2 = tid & 31;
        const float4 xv = *(const float4*)(
            x + ((size_t)(2 * g + b2) * TT + 0) * II + 4 * l2);
        *(float4*)(z + b2 * Z_STRIDE + 4 * l2) = xv;
    }
    __syncthreads();

    for (int t = 1; t <= TT; ++t) {
        float acc[2][4];
#pragma unroll
        for (int a = 0; a < 2; ++a)
#pragma unroll
            for (int b = 0; b < 4; ++b) acc[a][b] = 0.f;

        // ---- matvec over x rows (rr 0..1): h-independent, before the wait
#pragma unroll
        for (int rr = 0; rr < 2; ++rr)
#pragma unroll
            for (int bg = 0; bg < 2; ++bg) {
                const float4 zv = *(const float4*)(z + bg * Z_STRIDE + rr * 64 + rc * 4);
#pragma unroll
                for (int c = 0; c < 4; ++c)
                    acc[bg][c] += zv.x * wr[rr][0][c] + zv.y * wr[rr][1][c]
                                + zv.z * wr[rr][2][c] + zv.w * wr[rr][3][c];
            }

        // ---- tagged poll (waves 0,1 only): detect == data, unconditional loads
        if (t > 1 && w < 2) {
            const u32 want = (u32)(t - 1);
            const u64* hsrc = hbuf + ((size_t)((t - 1) & 1) * BB + myb) * HH;
            u64 n0, n1, n2, n3;
            int it = 0, ab = 0;
            for (;;) {
                n0 = HLOAD(hsrc + lane);       n1 = HLOAD(hsrc + lane + 64);
                n2 = HLOAD(hsrc + lane + 128); n3 = HLOAD(hsrc + lane + 192);
                const bool ok = ((u32)(n0 >> 32) == want) && ((u32)(n1 >> 32) == want)
                             && ((u32)(n2 >> 32) == want) && ((u32)(n3 >> 32) == want);
                if (__ballot(ok) == ~0ULL) break;
                if ((++it & 63) == 0) {
                    int abv = HLOAD(abortp);
                    if (abv) { ab = 1; break; }
                    if (it > (1 << 19)) {
                        if (lane == 0)
                            __hip_atomic_store(abortp, 1, __ATOMIC_RELAXED,
                                               __HIP_MEMORY_SCOPE_AGENT);
                        ab = 1; break;
                    }
                }
            }
            if (ab && lane == 0) misc[w] = 1;
            float* zdst = z + (w & 1) * Z_STRIDE + II + lane;
            zdst[0]   = __uint_as_float((u32)n0);
            zdst[64]  = __uint_as_float((u32)n1);
            zdst[128] = __uint_as_float((u32)n2);
            zdst[192] = __uint_as_float((u32)n3);
        }
        __syncthreads();                         // B1: z h-strips ready
        if (misc[0] | misc[1]) break;

        // ---- matvec over h rows (rr 2..5)
#pragma unroll
        for (int rr = 2; rr < 6; ++rr)
#pragma unroll
            for (int bg = 0; bg < 2; ++bg) {
                const float4 zv = *(const float4*)(z + bg * Z_STRIDE + rr * 64 + rc * 4);
#pragma unroll
                for (int c = 0; c < 4; ++c)
                    acc[bg][c] += zv.x * wr[rr][0][c] + zv.y * wr[rr][1][c]
                                + zv.z * wr[rr][2][c] + zv.w * wr[rr][3][c];
            }

        // ---- partials to LDS
#pragma unroll
        for (int bg = 0; bg < 2; ++bg)
#pragma unroll
            for (int c = 0; c < 4; ++c)
                part[rc * PART_RC_STRIDE + bg * PART_BG_STRIDE + cg * 4 + c] = acc[bg][c];
        __syncthreads();                         // B2: partials visible

        // ---- waves 0,1: reduce + shfl gates + tagged publish; waves 2,3: x stage
        if (w < 2) {
            float s = bia_reg;
#pragma unroll
            for (int r2 = 0; r2 < 16; ++r2)
                s += part[r2 * PART_RC_STRIDE + w * PART_BG_STRIDE + lane];

            const float sf = __shfl(s, j + 16);
            const float sg = __shfl(s, j + 32);
            const float so = __shfl(s, j + 48);
            if (lane < 16) {
                const float iv = sigm(s);
                const float fv = sigm(sf);
                const float gv = ftanh(sg);
                const float ov = sigm(so);
                creg = fv * creg + iv * gv;
                const float hv = ov * ftanh(creg);
                const u64 pk = ((u64)(u32)t << 32) | (u64)__float_as_uint(hv);
                __hip_atomic_store(
                    hbuf + ((size_t)(t & 1) * BB + myb) * HH + p * 16 + j,
                    pk, __ATOMIC_RELAXED, __HIP_MEMORY_SCOPE_AGENT);
            }
        } else if (t < TT && lane < 32) {
            // wave 2 stages batch 2g, wave 3 stages batch 2g+1
            const int b2 = w - 2;
            const float4 xv = *(const float4*)(
                x + ((size_t)(2 * g + b2) * TT + t) * II + 4 * lane);
            *(float4*)(z + b2 * Z_STRIDE + 4 * lane) = xv;
        }
        __syncthreads();                         // B3: x_{t+1} staged, z reusable
    }
}

extern "C" __global__ void __launch_bounds__(256) lstm_out(
    const float* __restrict__ wsf, const float* __restrict__ dw,
    const float* __restrict__ db, float* __restrict__ out)
{
    __shared__ float hs[256];
    __shared__ float red[256];
    const int b = blockIdx.x;
    const int tid = threadIdx.x;
    const u64* h0 = (const u64*)((const char*)wsf + WS_HBUF_B);  // parity 0 = h_1024
    hs[tid] = __uint_as_float((u32)h0[(size_t)b * HH + tid]);
    __syncthreads();
    const int o = tid & 127, half = tid >> 7;
    const float* wrow = dw + o * HH + half * 128;
    const float* hrow = hs + half * 128;
    float s = 0.f;
#pragma unroll
    for (int k = 0; k < 128; k += 4) {
        const float4 wv = *(const float4*)(wrow + k);
        s += hrow[k] * wv.x + hrow[k + 1] * wv.y + hrow[k + 2] * wv.z + hrow[k + 3] * wv.w;
    }
    red[tid] = s;
    __syncthreads();
    if (tid < 128)
        out[(size_t)b * OO + tid] = red[tid] + red[128 + tid] + db[tid];
}

extern "C" void kernel_launch(void* const* d_in, const int* in_sizes, int n_in,
                              void* d_out, int out_size, void* d_ws, size_t ws_size,
                              hipStream_t stream)
{
    const float* x    = (const float*)d_in[0];
    const float* W    = (const float*)d_in[1];
    const float* U    = (const float*)d_in[2];
    const float* bias = (const float*)d_in[3];
    const float* dw   = (const float*)d_in[4];
    const float* db   = (const float*)d_in[5];
    float* out = (float*)d_out;
    float* ws  = (float*)d_ws;

    // zero abort + tagged hbuf each call (tag=0 never matches t>=1)
    hipMemsetAsync(d_ws, 0, WS_CLEAR_B, stream);
    hipLaunchKernelGGL(lstm_scan, dim3(512), dim3(256), 0, stream,
                       x, W, U, bias, ws);
    hipLaunchKernelGGL(lstm_out, dim3(64), dim3(256), 0, stream, ws, dw, db, out);
}

// Round 15
// 2113.369 us; speedup vs baseline: 1.0849x; 1.0447x over previous
//
#include <hip/hip_runtime.h>
#include <math.h>

#define TT 1024
#define BB 64
#define II 128
#define HH 256
#define OO 128
#define GPB 16           // blocks (members) per group
#define NCOL 64          // gate-columns per block
#define Z_STRIDE 392     // padded z row stride per batch (floats)
#define PART_BG_STRIDE 68
#define PART_RC_STRIDE 273

// ws layout: abort @int 0; tagged hbuf [2][64][256] u64 @byte 16384 (256KB)
#define WS_HBUF_B 16384
#define WS_CLEAR_B (WS_HBUF_B + 2 * BB * HH * 8)

typedef unsigned long long u64;
typedef unsigned int u32;

__device__ __forceinline__ float rcp(float v) { return __builtin_amdgcn_rcpf(v); }
__device__ __forceinline__ float sigm(float v) { return rcp(1.f + __expf(-v)); }
__device__ __forceinline__ float ftanh(float v) {
    return __builtin_fmaf(-2.f, rcp(__expf(2.f * v) + 1.f), 1.f);
}

extern "C" __global__ void __launch_bounds__(256, 1) lstm_scan(
    const float* __restrict__ x, const float* __restrict__ W,
    const float* __restrict__ U, const float* __restrict__ bias,
    float* __restrict__ wsf)
{
    __shared__ float z[4 * Z_STRIDE];
    __shared__ float part[16 * PART_RC_STRIDE];
    __shared__ int   misc[8];

    int* abortp = (int*)wsf;
    u64* hbuf   = (u64*)((char*)wsf + WS_HBUF_B);   // [2][64][256] tagged

    const int tid  = threadIdx.x;
    const int gid  = blockIdx.x & 15;     // group
    const int p    = blockIdx.x >> 4;     // member: owns h-indices [16p,16p+16)
    const int cg   = tid & 15;            // column group (4 logical cols)
    const int rc   = tid >> 4;            // row group
    const int lane = tid & 63;
    const int w    = tid >> 6;            // wave index == batch slot in group
    const int myb  = 4 * gid + w;         // this wave's batch
    const int j    = lane & 15;

    // ---- weights in VGPRs: wr[rr][i][c] = [W;U][rr*64+rc*4+i][cg*4+c]
    float wr[6][4][4];
    {
        const int c0 = cg * 4;
        const int gcol = (c0 >> 4) * HH + p * 16 + (c0 & 15);
#pragma unroll
        for (int rr = 0; rr < 6; ++rr) {
#pragma unroll
            for (int i = 0; i < 4; ++i) {
                const int r = rr * 64 + rc * 4 + i;
                const float4 wv = (rr < 2)
                    ? *(const float4*)(W + (size_t)r * 1024 + gcol)
                    : *(const float4*)(U + (size_t)(r - II) * 1024 + gcol);
                wr[rr][i][0] = wv.x; wr[rr][i][1] = wv.y;
                wr[rr][i][2] = wv.z; wr[rr][i][3] = wv.w;
            }
        }
    }
    // bias for this thread's reduce column (col = lane, same for all waves)
    const float bia_reg = bias[(lane >> 4) * HH + p * 16 + j];
    float creg = 0.f;                     // c-state: lanes 0..15 of each wave

    for (int idx = tid; idx < 4 * Z_STRIDE; idx += 256) z[idx] = 0.f;
    if (tid < 8) misc[tid] = 0;

    // ---- prologue: x_1 into z
    if (tid < 128) {
        const int b2 = tid >> 5, l2 = tid & 31;
        const float4 xv = *(const float4*)(
            x + ((size_t)(4 * gid + b2) * TT + 0) * II + 4 * l2);
        *(float4*)(z + b2 * Z_STRIDE + 4 * l2) = xv;
    }
    __syncthreads();

    for (int t = 1; t <= TT; ++t) {
        float acc[4][4];
#pragma unroll
        for (int a = 0; a < 4; ++a)
#pragma unroll
            for (int b = 0; b < 4; ++b) acc[a][b] = 0.f;

        // ---- matvec over x rows (rr 0..1): h-independent, before the wait
#pragma unroll
        for (int rr = 0; rr < 2; ++rr) {
#pragma unroll
            for (int bg = 0; bg < 4; ++bg) {
                const float4 zv = *(const float4*)(z + bg * Z_STRIDE + rr * 64 + rc * 4);
#pragma unroll
                for (int c = 0; c < 4; ++c)
                    acc[bg][c] += zv.x * wr[rr][0][c] + zv.y * wr[rr][1][c]
                                + zv.z * wr[rr][2][c] + zv.w * wr[rr][3][c];
            }
        }

        // ---- tagged poll: detect == data. UNCONDITIONAL 4-wide load rounds
        // (predicated reloads serialize atomic loads -> 4 RT/round: r6 bug)
        if (t > 1) {
            const u32 want = (u32)(t - 1);
            const u64* hsrc = hbuf + ((size_t)((t - 1) & 1) * BB + myb) * HH;
            u64 n0, n1, n2, n3;
            int it = 0, ab = 0;
            for (;;) {
                n0 = __hip_atomic_load(hsrc + lane,       __ATOMIC_RELAXED, __HIP_MEMORY_SCOPE_AGENT);
                n1 = __hip_atomic_load(hsrc + lane + 64,  __ATOMIC_RELAXED, __HIP_MEMORY_SCOPE_AGENT);
                n2 = __hip_atomic_load(hsrc + lane + 128, __ATOMIC_RELAXED, __HIP_MEMORY_SCOPE_AGENT);
                n3 = __hip_atomic_load(hsrc + lane + 192, __ATOMIC_RELAXED, __HIP_MEMORY_SCOPE_AGENT);
                const bool ok = ((u32)(n0 >> 32) == want) && ((u32)(n1 >> 32) == want)
                             && ((u32)(n2 >> 32) == want) && ((u32)(n3 >> 32) == want);
                if (__ballot(ok) == ~0ULL) break;
                if ((++it & 63) == 0) {
                    int abv = __hip_atomic_load(abortp, __ATOMIC_RELAXED,
                                                __HIP_MEMORY_SCOPE_AGENT);
                    if (abv) { ab = 1; break; }
                    if (it > (1 << 19)) {
                        if (lane == 0)
                            __hip_atomic_store(abortp, 1, __ATOMIC_RELAXED,
                                               __HIP_MEMORY_SCOPE_AGENT);
                        ab = 1; break;
                    }
                }
            }
            if (ab && lane == 0) misc[w] = 1;
            float* zdst = z + w * Z_STRIDE + II + lane;
            zdst[0]   = __uint_as_float((u32)n0);
            zdst[64]  = __uint_as_float((u32)n1);
            zdst[128] = __uint_as_float((u32)n2);
            zdst[192] = __uint_as_float((u32)n3);
        }
        __syncthreads();                         // (1) all z h-parts written
        if (misc[0] | misc[1] | misc[2] | misc[3]) break;

        // ---- matvec over h rows (rr 2..5)
#pragma unroll
        for (int rr = 2; rr < 6; ++rr) {
#pragma unroll
            for (int bg = 0; bg < 4; ++bg) {
                const float4 zv = *(const float4*)(z + bg * Z_STRIDE + rr * 64 + rc * 4);
#pragma unroll
                for (int c = 0; c < 4; ++c)
                    acc[bg][c] += zv.x * wr[rr][0][c] + zv.y * wr[rr][1][c]
                                + zv.z * wr[rr][2][c] + zv.w * wr[rr][3][c];
            }
        }

        // ---- partials to LDS
#pragma unroll
        for (int bg = 0; bg < 4; ++bg)
#pragma unroll
            for (int c = 0; c < 4; ++c)
                part[rc * PART_RC_STRIDE + bg * PART_BG_STRIDE + cg * 4 + c] = acc[bg][c];
        __syncthreads();                         // (2) partials visible

        // ---- per-wave reduce (batch w, col = lane) + shfl gates + tagged publish
        float s = bia_reg;
#pragma unroll
        for (int r2 = 0; r2 < 16; ++r2)
            s += part[r2 * PART_RC_STRIDE + w * PART_BG_STRIDE + lane];

        const float sf = __shfl(s, j + 16);
        const float sg = __shfl(s, j + 32);
        const float so = __shfl(s, j + 48);
        if (lane < 16) {
            const float iv = sigm(s);
            const float fv = sigm(sf);
            const float gv = ftanh(sg);
            const float ov = sigm(so);
            creg = fv * creg + iv * gv;
            const float hv = ov * ftanh(creg);
            const u64 pk = ((u64)(u32)t << 32) | (u64)__float_as_uint(hv);
            __hip_atomic_store(
                hbuf + ((size_t)(t & 1) * BB + myb) * HH + p * 16 + j,
                pk, __ATOMIC_RELAXED, __HIP_MEMORY_SCOPE_AGENT);
        } else if (lane < 48 && t < TT) {
            // x_{t+1} prefetch for this wave's batch
            const int l2 = lane - 16;
            const float4 xv = *(const float4*)(
                x + ((size_t)myb * TT + t) * II + 4 * l2);
            *(float4*)(z + w * Z_STRIDE + 4 * l2) = xv;
        }
        __syncthreads();                         // (3) x_{t+1} staged; z reusable
    }
}

extern "C" __global__ void __launch_bounds__(256) lstm_out(
    const float* __restrict__ wsf, const float* __restrict__ dw,
    const float* __restrict__ db, float* __restrict__ out)
{
    __shared__ float hs[256];
    __shared__ float red[256];
    const int b = blockIdx.x;
    const int tid = threadIdx.x;
    const u64* h0 = (const u64*)((const char*)wsf + WS_HBUF_B);  // parity 0 = h_1024
    hs[tid] = __uint_as_float((u32)h0[(size_t)b * HH + tid]);
    __syncthreads();
    const int o = tid & 127, half = tid >> 7;
    const float* wrow = dw + o * HH + half * 128;
    const float* hrow = hs + half * 128;
    float s = 0.f;
#pragma unroll
    for (int k = 0; k < 128; k += 4) {
        const float4 wv = *(const float4*)(wrow + k);
        s += hrow[k] * wv.x + hrow[k + 1] * wv.y + hrow[k + 2] * wv.z + hrow[k + 3] * wv.w;
    }
    red[tid] = s;
    __syncthreads();
    if (tid < 128)
        out[(size_t)b * OO + tid] = red[tid] + red[128 + tid] + db[tid];
}

extern "C" void kernel_launch(void* const* d_in, const int* in_sizes, int n_in,
                              void* d_out, int out_size, void* d_ws, size_t ws_size,
                              hipStream_t stream)
{
    const float* x    = (const float*)d_in[0];
    const float* W    = (const float*)d_in[1];
    const float* U    = (const float*)d_in[2];
    const float* bias = (const float*)d_in[3];
    const float* dw   = (const float*)d_in[4];
    const float* db   = (const float*)d_in[5];
    float* out = (float*)d_out;
    float* ws  = (float*)d_ws;

    // zero abort + tagged hbuf each call (tag=0 never matches t>=1 ->
    // no cross-replay staleness)
    hipMemsetAsync(d_ws, 0, WS_CLEAR_B, stream);
    hipLaunchKernelGGL(lstm_scan, dim3(256), dim3(256), 0, stream,
                       x, W, U, bias, ws);
    hipLaunchKernelGGL(lstm_out, dim3(64), dim3(256), 0, stream, ws, dw, db, out);
}